// Round 12
// baseline (255.503 us; speedup 1.0000x reference)
//
#include <hip/hip_runtime.h>

#define T_LEN 262144
#define B_SZ 8
#define CHUNK 8192
#define HALO 4096
#define NTHREADS 1024
#define NGROUPS ((CHUNK + HALO) / 4)    // 3072 4-element groups per frame
#define CPR (T_LEN / CHUNK)             // 32 chunks per row
#define NBLOCKS (B_SZ * CPR)            // 256 = one block per CU (all resident)
#define LOG2E 1.4426950408889634f
#define NEG2LOG2E (-2.8853900817779268f)
#define NEGLOG2E  (-1.4426950408889634f)

typedef float f32x2 __attribute__((ext_vector_type(2)));
typedef float f32x4 __attribute__((ext_vector_type(4)));
typedef _Float16 f16x2 __attribute__((ext_vector_type(2)));
typedef __fp16 fp16x2 __attribute__((ext_vector_type(2)));

__device__ __forceinline__ float frcp(float x)  { return __builtin_amdgcn_rcpf(x); }
__device__ __forceinline__ float fexp2(float x) { return __builtin_amdgcn_exp2f(x); }
__device__ __forceinline__ f32x2 pair(float s)  { f32x2 r = {s, s}; return r; }
__device__ __forceinline__ f32x2 lo2(f32x4 v)   { return __builtin_shufflevector(v, v, 0, 1); }
__device__ __forceinline__ f32x2 hi2(f32x4 v)   { return __builtin_shufflevector(v, v, 2, 3); }
__device__ __forceinline__ f32x4 cat4(f32x2 a, f32x2 b) {
    f32x4 r; r.x = a.x; r.y = a.y; r.z = b.x; r.w = b.y; return r;
}
__device__ __forceinline__ unsigned b32(f16x2 v) { return __builtin_bit_cast(unsigned, v); }
__device__ __forceinline__ f16x2 hbits(unsigned u) { return __builtin_bit_cast(f16x2, u); }
__device__ __forceinline__ f16x2 hsplat(float s) { _Float16 h = (_Float16)s; f16x2 r = {h, h}; return r; }
__device__ __forceinline__ f16x2 hfma(f16x2 a, f16x2 b, f16x2 c) { return __builtin_elementwise_fma(a, b, c); }
__device__ __forceinline__ f16x2 pkrtz(float x, float y) {
    fp16x2 t = __builtin_amdgcn_cvt_pkrtz(x, y);
    return __builtin_bit_cast(f16x2, t);
}
__device__ __forceinline__ f32x4 h2f4(f16x2 a, f16x2 b) {
    f32x2 lo = __builtin_convertvector(a, f32x2);
    f32x2 hi = __builtin_convertvector(b, f32x2);
    return cat4(lo, hi);
}

// packed-FP32 VOP3P asm (round-8 lesson: sources must be VGPRs, never SGPRs)
__device__ __forceinline__ f32x2 pkfma2(f32x2 a, f32x2 b, f32x2 c) {
    f32x2 d;
    asm("v_pk_fma_f32 %0, %1, %2, %3" : "=v"(d) : "v"(a), "v"(b), "v"(c));
    return d;
}
__device__ __forceinline__ f32x2 pkadd2(f32x2 a, f32x2 b) {
    f32x2 d;
    asm("v_pk_add_f32 %0, %1, %2" : "=v"(d) : "v"(a), "v"(b));
    return d;
}
__device__ __forceinline__ f32x2 pksub2(f32x2 a, f32x2 b) {  // a - b
    f32x2 d;
    asm("v_pk_add_f32 %0, %1, %2 neg_lo:[0,1] neg_hi:[0,1]" : "=v"(d) : "v"(a), "v"(b));
    return d;
}
__device__ __forceinline__ f32x2 pkmul2(f32x2 a, f32x2 b) {
    f32x2 d;
    asm("v_pk_mul_f32 %0, %1, %2" : "=v"(d) : "v"(a), "v"(b));
    return d;
}
__device__ __forceinline__ f32x4 pfma_v(f32x4 a, f32x4 b, f32x4 c) {
    return cat4(pkfma2(lo2(a), lo2(b), lo2(c)), pkfma2(hi2(a), hi2(b), hi2(c)));
}
__device__ __forceinline__ f32x4 padd_s(f32x2 s, f32x4 b) {
    return cat4(pkadd2(s, lo2(b)), pkadd2(s, hi2(b)));
}
__device__ __forceinline__ f32x4 psub_s(f32x2 s, f32x4 b) {  // s - b
    return cat4(pksub2(s, lo2(b)), pksub2(s, hi2(b)));
}
__device__ __forceinline__ f32x4 pmul_v(f32x4 a, f32x4 b) {
    return cat4(pkmul2(lo2(a), lo2(b)), pkmul2(hi2(a), hi2(b)));
}

// o = tanh(a)*sigmoid(b); af, ag arrive pre-scaled by -2log2e / -log2e
__device__ __forceinline__ f32x4 gate4(f32x4 af, f32x4 ag, f32x2 one) {
    f32x4 E1, E2, rc;
    E1.x = fexp2(af.x); E1.y = fexp2(af.y); E1.z = fexp2(af.z); E1.w = fexp2(af.w);
    E2.x = fexp2(ag.x); E2.y = fexp2(ag.y); E2.z = fexp2(ag.z); E2.w = fexp2(ag.w);
    f32x4 d1  = padd_s(one, E1);
    f32x4 den = pfma_v(E2, d1, d1);
    f32x4 num = psub_s(one, E1);
    rc.x = frcp(den.x); rc.y = frcp(den.y); rc.z = frcp(den.z); rc.w = frcp(den.w);
    return pmul_v(num, rc);
}
__device__ __forceinline__ float mulaw(float v, float c1wv, float c1bv, float c2wv, float c2bv) {
    float a  = __builtin_fmaf(c1wv, fmaxf(v, 0.0f), c1bv);
    float b2 = __builtin_fmaf(c2wv, fmaxf(a, 0.0f), c2bv);
    float m  = fexp2(fabsf(b2) * 8.0f) - 1.0f;
    return copysignf(m * (1.0f / 255.0f), b2);
}

__global__ __launch_bounds__(64)
void init_flags(unsigned* flags)
{
    for (int i = threadIdx.x; i < 2 * NBLOCKS + B_SZ; i += 64) flags[i] = 0u;
}

// One 10-layer dilation cycle (identical math to round 11). CSTART = parity
// of the LDS buffer read by layer 0.
template <int CSTART>
__device__ __forceinline__ void run_cycle(
    int Lbase, int tid, bool first,
    const float* __restrict__ fw, const float* __restrict__ gw,
    const float* __restrict__ fb, const float* __restrict__ gb,
    const float* __restrict__ rw, const float* __restrict__ rb,
    f16x2 (&hA)[3], f16x2 (&hB)[3],
    f16x2 &s1A, f16x2 &s1B, f16x2 &s2A, f16x2 &s2B,
    uint2 (*bufl)[NGROUPS])
{
    const f32x2 ONE = pair(1.0f);
    const f16x2 HZ = hsplat(0.0f);
    #pragma unroll
    for (int k = 0; k < 10; ++k) {
        const int c = (k + CSTART) & 1;
        const int d = 1 << k;
        const int L = Lbase + k;
        const float* fwL = fw + 5 * L;
        const float* gwL = gw + 5 * L;
        const f16x2 WF0 = hsplat(fwL[4] * NEG2LOG2E), WF1 = hsplat(fwL[3] * NEG2LOG2E),
                    WF2 = hsplat(fwL[2] * NEG2LOG2E), WF3 = hsplat(fwL[1] * NEG2LOG2E),
                    WF4 = hsplat(fwL[0] * NEG2LOG2E);
        const f16x2 WG0 = hsplat(gwL[4] * NEGLOG2E), WG1 = hsplat(gwL[3] * NEGLOG2E),
                    WG2 = hsplat(gwL[2] * NEGLOG2E), WG3 = hsplat(gwL[1] * NEGLOG2E),
                    WG4 = hsplat(gwL[0] * NEGLOG2E);
        const f16x2 FB = hsplat(fb[L] * NEG2LOG2E), GB = hsplat(gb[L] * NEGLOG2E);
        const f16x2 RW = hsplat(rw[L]), RB = hsplat(rb[L]);
        const uint2* __restrict__ bufc = bufl[c];
        uint2* __restrict__ bufd = bufl[c ^ 1];

        #pragma unroll
        for (int w = 0; w < 3; ++w) {
            const int G = tid + w * NTHREADS;
            if (w == 0 && tid < (2 << k)) continue;  // reach-based halo skip
            f16x2 cA = hA[w], cB = hB[w];
            f16x2 t1a, t1b, t2a, t2b, t3a, t3b, t4a, t4b;
            if (d >= 4) {
                const int DG = d >> 2;
                const uint2* bp = bufc + (G - 4 * DG);
                uint2 U4 = bp[0], U3 = bp[DG], U2 = bp[2 * DG], U1 = bp[3 * DG];
                t1a = hbits(U1.x); t1b = hbits(U1.y);
                t2a = hbits(U2.x); t2b = hbits(U2.y);
                t3a = hbits(U3.x); t3b = hbits(U3.y);
                t4a = hbits(U4.x); t4b = hbits(U4.y);
            } else if (d == 1) {
                uint2 P = bufc[G - 1];
                unsigned uA = b32(cA);
                unsigned w1A = __builtin_amdgcn_perm(uA, P.y, 0x05040302u);
                unsigned w1B = __builtin_amdgcn_perm(b32(cB), uA, 0x05040302u);
                unsigned w3A = __builtin_amdgcn_perm(P.y, P.x, 0x05040302u);
                t1a = hbits(w1A); t1b = hbits(w1B);
                t2a = hbits(P.y); t2b = cA;
                t3a = hbits(w3A); t3b = hbits(w1A);
                t4a = hbits(P.x); t4b = hbits(P.y);
            } else { // d == 2
                uint2 P = bufc[G - 1], Q = bufc[G - 2];
                t1a = hbits(P.y); t1b = cA;
                t2a = hbits(P.x); t2b = hbits(P.y);
                t3a = hbits(Q.y); t3b = hbits(P.x);
                t4a = hbits(Q.x); t4b = hbits(Q.y);
            }
            f16x2 afA = hfma(WF0, cA, FB), afB = hfma(WF0, cB, FB);
            afA = hfma(WF1, t1a, afA); afB = hfma(WF1, t1b, afB);
            afA = hfma(WF2, t2a, afA); afB = hfma(WF2, t2b, afB);
            afA = hfma(WF3, t3a, afA); afB = hfma(WF3, t3b, afB);
            afA = hfma(WF4, t4a, afA); afB = hfma(WF4, t4b, afB);
            f16x2 agA = hfma(WG0, cA, GB), agB = hfma(WG0, cB, GB);
            agA = hfma(WG1, t1a, agA); agB = hfma(WG1, t1b, agB);
            agA = hfma(WG2, t2a, agA); agB = hfma(WG2, t2b, agB);
            agA = hfma(WG3, t3a, agA); agB = hfma(WG3, t3b, agB);
            agA = hfma(WG4, t4a, agA); agB = hfma(WG4, t4b, agB);
            f32x4 o = gate4(h2f4(afA, afB), h2f4(agA, agB), ONE);
            f16x2 oA = pkrtz(o.x, o.y), oB = pkrtz(o.z, o.w);
            f16x2 nA = hfma(RW, oA, cA + RB);
            f16x2 nB = hfma(RW, oB, cB + RB);
            if (w == 0 && first) { nA = HZ; nB = HZ; }   // t<0 padding exact 0
            hA[w] = nA; hB[w] = nB;
            if (k < 9) bufd[G] = make_uint2(b32(nA), b32(nB));
            if (w == 1) { s1A = s1A + oA; s1B = s1B + oB; }
            if (w == 2) { s2A = s2A + oA; s2B = s2B + oB; }
        }
        if (k < 9) __syncthreads();
    }
}

// Persistent fused kernel: all 3 cycles + epilogue + softmax in ONE launch.
// 256 blocks (= #CUs, all resident -> flag spin is deadlock-free). Between
// cycles a block publishes only its RIGHT HALF h (8 KB packed f16) and spins
// for its left neighbor's; h/sk stay in registers. Cross-XCD safety:
// per-thread __threadfence (release) before the flag atomic; atomic RMW spin
// + __threadfence (acquire) after. Flags zeroed per call by init_flags.
// Epilogue: per-row atomic counter, then every row block reduces the 32
// (max, sumexp) stats redundantly and writes softmax directly from registers
// (pre-softmax values never touch HBM).
__global__ __launch_bounds__(NTHREADS, 4)
void wavenet_fused(const float* __restrict__ x,
                   const float* __restrict__ cw, const float* __restrict__ cb,
                   const float* __restrict__ fw, const float* __restrict__ fb,
                   const float* __restrict__ gw, const float* __restrict__ gb,
                   const float* __restrict__ rw, const float* __restrict__ rb,
                   const float* __restrict__ c1w, const float* __restrict__ c1b,
                   const float* __restrict__ c2w, const float* __restrict__ c2b,
                   uint2* __restrict__ halo0, uint2* __restrict__ halo1,
                   float2* __restrict__ bs, unsigned* __restrict__ flags,
                   float* __restrict__ out)
{
    __shared__ uint2 bufl[2][NGROUPS];       // 2 x 24 KB packed-f16 tap buffers
    __shared__ float red[NTHREADS / 64];

    const int tid = threadIdx.x;
    const int bid = blockIdx.x;
    const int row = bid / CPR;
    const int ci  = bid % CPR;
    const int rowbase = row * T_LEN;
    const int base_t = ci * CHUNK;
    const bool first = (ci == 0);
    const f16x2 HZ = hsplat(0.0f);
    unsigned* rowcnt = flags + 2 * NBLOCKS;

    // ---- stage 0 prologue: load x (f32), pack, publish taps ----
    f16x2 hA[3], hB[3];
    {
        const float* inb = x + rowbase + base_t - HALO;
        #pragma unroll
        for (int w = 0; w < 3; ++w) {
            int G = tid + w * NTHREADS;
            if (w == 0 && first) { hA[w] = HZ; hB[w] = HZ; }
            else {
                f32x4 v = *(const f32x4*)(inb + 4 * G);
                hA[w] = pkrtz(v.x, v.y);
                hB[w] = pkrtz(v.z, v.w);
            }
            bufl[0][G] = make_uint2(b32(hA[w]), b32(hB[w]));
        }
    }
    f16x2 s1A = HZ, s1B = HZ, s2A = HZ, s2B = HZ;
    __syncthreads();

    // ---- causal conv (d=1); weight for tap distance m is cw[4-m] ----
    {
        const f16x2 C0 = hsplat(cw[4]), C1 = hsplat(cw[3]), C2 = hsplat(cw[2]),
                    C3 = hsplat(cw[1]), C4 = hsplat(cw[0]), BB = hsplat(cb[0]);
        #pragma unroll
        for (int w = 0; w < 3; ++w) {
            int G = tid + w * NTHREADS;
            int gm = G - 1; if (w == 0) gm = gm < 0 ? 0 : gm;  // junk-in-halo OK
            uint2 P = bufl[0][gm];
            unsigned uA = b32(hA[w]), uB = b32(hB[w]);
            unsigned t1A = __builtin_amdgcn_perm(uA, P.y, 0x05040302u);
            unsigned t1B = __builtin_amdgcn_perm(uB, uA, 0x05040302u);
            unsigned t3A = __builtin_amdgcn_perm(P.y, P.x, 0x05040302u);
            f16x2 aA = hfma(C0, hA[w], BB);
            f16x2 aB = hfma(C0, hB[w], BB);
            aA = hfma(C1, hbits(t1A), aA); aB = hfma(C1, hbits(t1B), aB);
            aA = hfma(C2, hbits(P.y), aA); aB = hfma(C2, hbits(uA), aB);
            aA = hfma(C3, hbits(t3A), aA); aB = hfma(C3, hbits(t1A), aB);
            aA = hfma(C4, hbits(P.x), aA); aB = hfma(C4, hbits(P.y), aB);
            if (w == 0 && first) { aA = HZ; aB = HZ; }
            hA[w] = aA; hB[w] = aB;
            bufl[1][G] = make_uint2(b32(aA), b32(aB));
        }
        __syncthreads();
    }

    // ---- cycle 0 (layers 0-9) ----
    run_cycle<1>(0, tid, first, fw, gw, fb, gb, rw, rb, hA, hB, s1A, s1B, s2A, s2B, bufl);

    // ---- publish right-half h, flag, spin for left neighbor, reload LDS ----
    #pragma unroll
    for (int s = 0; s < 2; ++s) {
        uint2* halo = (s == 0) ? halo0 : halo1;
        unsigned* flg = flags + s * NBLOCKS;
        halo[(unsigned)bid * 1024u + tid] = make_uint2(b32(hA[2]), b32(hB[2]));
        __threadfence();                      // device-scope release of halo
        __syncthreads();
        if (tid == 0) atomicExch(&flg[bid], 1u);
        if (!first) {
            if (tid == 0) {
                while (atomicAdd(&flg[bid - 1], 0u) == 0u) __builtin_amdgcn_s_sleep(1);
                __threadfence();              // acquire: invalidate stale lines
            }
            __syncthreads();
        }
        uint2 u0 = first ? make_uint2(0u, 0u) : halo[(unsigned)(bid - 1) * 1024u + tid];
        hA[0] = hbits(u0.x); hB[0] = hbits(u0.y);
        bufl[0][tid]        = u0;
        bufl[0][tid + 1024] = make_uint2(b32(hA[1]), b32(hB[1]));
        bufl[0][tid + 2048] = make_uint2(b32(hA[2]), b32(hB[2]));
        __syncthreads();
        run_cycle<0>(10 * (s + 1), tid, first, fw, gw, fb, gb, rw, rb,
                     hA, hB, s1A, s1B, s2A, s2B, bufl);
    }

    // ---- fused epilogue: mu-law + per-block stats ----
    const float c1wv = c1w[0], c1bv = c1b[0], c2wv = c2w[0], c2bv = c2b[0];
    f32x4 sk1 = h2f4(s1A, s1B), sk2 = h2f4(s2A, s2B);
    f32x4 p1, p2;
    p1.x = mulaw(sk1.x, c1wv, c1bv, c2wv, c2bv);
    p1.y = mulaw(sk1.y, c1wv, c1bv, c2wv, c2bv);
    p1.z = mulaw(sk1.z, c1wv, c1bv, c2wv, c2bv);
    p1.w = mulaw(sk1.w, c1wv, c1bv, c2wv, c2bv);
    p2.x = mulaw(sk2.x, c1wv, c1bv, c2wv, c2bv);
    p2.y = mulaw(sk2.y, c1wv, c1bv, c2wv, c2bv);
    p2.z = mulaw(sk2.z, c1wv, c1bv, c2wv, c2bv);
    p2.w = mulaw(sk2.w, c1wv, c1bv, c2wv, c2bv);

    float pmax = fmaxf(fmaxf(fmaxf(p1.x, p1.y), fmaxf(p1.z, p1.w)),
                       fmaxf(fmaxf(p2.x, p2.y), fmaxf(p2.z, p2.w)));
    #pragma unroll
    for (int off = 32; off; off >>= 1) pmax = fmaxf(pmax, __shfl_xor(pmax, off, 64));
    if ((tid & 63) == 0) red[tid >> 6] = pmax;
    __syncthreads();
    float bmax = red[0];
    #pragma unroll
    for (int i = 1; i < NTHREADS / 64; ++i) bmax = fmaxf(bmax, red[i]);
    __syncthreads();   // red reused below

    float ps = fexp2((p1.x - bmax) * LOG2E) + fexp2((p1.y - bmax) * LOG2E)
             + fexp2((p1.z - bmax) * LOG2E) + fexp2((p1.w - bmax) * LOG2E)
             + fexp2((p2.x - bmax) * LOG2E) + fexp2((p2.y - bmax) * LOG2E)
             + fexp2((p2.z - bmax) * LOG2E) + fexp2((p2.w - bmax) * LOG2E);
    #pragma unroll
    for (int off = 32; off; off >>= 1) ps += __shfl_xor(ps, off, 64);
    if ((tid & 63) == 0) red[tid >> 6] = ps;
    __syncthreads();

    // ---- row-wide rendezvous: publish stats, wait for all 32 row blocks ----
    if (tid == 0) {
        float s = 0.0f;
        #pragma unroll
        for (int i = 0; i < NTHREADS / 64; ++i) s += red[i];
        bs[bid] = make_float2(bmax, s);
        __threadfence();
        atomicAdd(&rowcnt[row], 1u);
        while (atomicAdd(&rowcnt[row], 0u) < (unsigned)CPR) __builtin_amdgcn_s_sleep(1);
        __threadfence();
    }
    __syncthreads();

    // every thread reduces the row's 32 stats (L1-hot) and normalizes its own
    float m = -3.0e38f;
    for (int j = 0; j < CPR; ++j) m = fmaxf(m, bs[row * CPR + j].x);
    float cc = 0.0f;
    for (int j = 0; j < CPR; ++j) {
        float2 v = bs[row * CPR + j];
        cc += v.y * fexp2((v.x - m) * LOG2E);
    }
    const float inv = 1.0f / cc;

    f32x4 q1, q2;
    q1.x = fexp2((p1.x - m) * LOG2E) * inv;
    q1.y = fexp2((p1.y - m) * LOG2E) * inv;
    q1.z = fexp2((p1.z - m) * LOG2E) * inv;
    q1.w = fexp2((p1.w - m) * LOG2E) * inv;
    q2.x = fexp2((p2.x - m) * LOG2E) * inv;
    q2.y = fexp2((p2.y - m) * LOG2E) * inv;
    q2.z = fexp2((p2.z - m) * LOG2E) * inv;
    q2.w = fexp2((p2.w - m) * LOG2E) * inv;
    *(f32x4*)(out + rowbase + base_t + 4 * tid)        = q1;
    *(f32x4*)(out + rowbase + base_t + 4096 + 4 * tid) = q2;
}

extern "C" void kernel_launch(void* const* d_in, const int* in_sizes, int n_in,
                              void* d_out, int out_size, void* d_ws, size_t ws_size,
                              hipStream_t stream)
{
    (void)in_sizes; (void)n_in; (void)out_size; (void)ws_size;
    const float* x   = (const float*)d_in[0];
    const float* cw  = (const float*)d_in[1];
    const float* cb  = (const float*)d_in[2];
    const float* fw  = (const float*)d_in[3];
    const float* fb  = (const float*)d_in[4];
    const float* gw  = (const float*)d_in[5];
    const float* gb  = (const float*)d_in[6];
    const float* rw  = (const float*)d_in[7];
    const float* rb  = (const float*)d_in[8];
    const float* c1w = (const float*)d_in[9];
    const float* c1b = (const float*)d_in[10];
    const float* c2w = (const float*)d_in[11];
    const float* c2b = (const float*)d_in[12];
    float* out = (float*)d_out;

    uint2*    halo0 = (uint2*)d_ws;                                   // 2 MB
    uint2*    halo1 = (uint2*)((char*)d_ws + (NBLOCKS * 1024 * 8));   // 2 MB
    float2*   bs    = (float2*)((char*)d_ws + 2 * (NBLOCKS * 1024 * 8));
    unsigned* flags = (unsigned*)((char*)d_ws + 2 * (NBLOCKS * 1024 * 8) + 4096);

    init_flags<<<1, 64, 0, stream>>>(flags);
    wavenet_fused<<<NBLOCKS, NTHREADS, 0, stream>>>(x, cw, cb, fw, fb, gw, gb, rw, rb,
                                                    c1w, c1b, c2w, c2b,
                                                    halo0, halo1, bs, flags, out);
}

// Round 13
// 80.501 us; speedup vs baseline: 3.1739x; 3.1739x over previous
//
#include <hip/hip_runtime.h>

#define T_LEN 262144
#define B_SZ 8
#define CHUNK 8192
#define HALO 4096
#define NTHREADS 512
#define NG 6                            // groups per thread (w=0,1 halo; 2..5 valid)
#define NGROUPS ((CHUNK + HALO) / 4)    // 3072 4-element groups per frame
#define CHUNKS_PER_ROW (T_LEN / CHUNK)  // 32
#define NBLOCKS (B_SZ * CHUNKS_PER_ROW) // 256 blocks of 512 -> 2 blocks/CU
#define LOG2E 1.4426950408889634f
#define NEG2LOG2E (-2.8853900817779268f)
#define NEGLOG2E  (-1.4426950408889634f)

typedef float f32x2 __attribute__((ext_vector_type(2)));
typedef float f32x4 __attribute__((ext_vector_type(4)));
typedef _Float16 f16x2 __attribute__((ext_vector_type(2)));
typedef __fp16 fp16x2 __attribute__((ext_vector_type(2)));

__device__ __forceinline__ float frcp(float x)  { return __builtin_amdgcn_rcpf(x); }
__device__ __forceinline__ float fexp2(float x) { return __builtin_amdgcn_exp2f(x); }
__device__ __forceinline__ f32x2 pair(float s)  { f32x2 r = {s, s}; return r; }
__device__ __forceinline__ f32x2 lo2(f32x4 v)   { return __builtin_shufflevector(v, v, 0, 1); }
__device__ __forceinline__ f32x2 hi2(f32x4 v)   { return __builtin_shufflevector(v, v, 2, 3); }
__device__ __forceinline__ f32x4 cat4(f32x2 a, f32x2 b) {
    f32x4 r; r.x = a.x; r.y = a.y; r.z = b.x; r.w = b.y; return r;
}
__device__ __forceinline__ unsigned b32(f16x2 v) { return __builtin_bit_cast(unsigned, v); }
__device__ __forceinline__ f16x2 hbits(unsigned u) { return __builtin_bit_cast(f16x2, u); }
__device__ __forceinline__ f16x2 hsplat(float s) { _Float16 h = (_Float16)s; f16x2 r = {h, h}; return r; }
__device__ __forceinline__ f16x2 hfma(f16x2 a, f16x2 b, f16x2 c) { return __builtin_elementwise_fma(a, b, c); }
__device__ __forceinline__ f16x2 pkrtz(float x, float y) {
    fp16x2 t = __builtin_amdgcn_cvt_pkrtz(x, y);
    return __builtin_bit_cast(f16x2, t);
}
__device__ __forceinline__ f32x4 h2f4(f16x2 a, f16x2 b) {
    f32x2 lo = __builtin_convertvector(a, f32x2);
    f32x2 hi = __builtin_convertvector(b, f32x2);
    return cat4(lo, hi);
}

// packed-FP32 VOP3P asm (round-8 lesson: sources must be VGPRs, never SGPRs)
__device__ __forceinline__ f32x2 pkfma2(f32x2 a, f32x2 b, f32x2 c) {
    f32x2 d;
    asm("v_pk_fma_f32 %0, %1, %2, %3" : "=v"(d) : "v"(a), "v"(b), "v"(c));
    return d;
}
__device__ __forceinline__ f32x2 pkadd2(f32x2 a, f32x2 b) {
    f32x2 d;
    asm("v_pk_add_f32 %0, %1, %2" : "=v"(d) : "v"(a), "v"(b));
    return d;
}
__device__ __forceinline__ f32x2 pksub2(f32x2 a, f32x2 b) {  // a - b
    f32x2 d;
    asm("v_pk_add_f32 %0, %1, %2 neg_lo:[0,1] neg_hi:[0,1]" : "=v"(d) : "v"(a), "v"(b));
    return d;
}
__device__ __forceinline__ f32x2 pkmul2(f32x2 a, f32x2 b) {
    f32x2 d;
    asm("v_pk_mul_f32 %0, %1, %2" : "=v"(d) : "v"(a), "v"(b));
    return d;
}
__device__ __forceinline__ f32x4 pfma_v(f32x4 a, f32x4 b, f32x4 c) {
    return cat4(pkfma2(lo2(a), lo2(b), lo2(c)), pkfma2(hi2(a), hi2(b), hi2(c)));
}
__device__ __forceinline__ f32x4 padd_s(f32x2 s, f32x4 b) {
    return cat4(pkadd2(s, lo2(b)), pkadd2(s, hi2(b)));
}
__device__ __forceinline__ f32x4 psub_s(f32x2 s, f32x4 b) {  // s - b
    return cat4(pksub2(s, lo2(b)), pksub2(s, hi2(b)));
}
__device__ __forceinline__ f32x4 pmul_v(f32x4 a, f32x4 b) {
    return cat4(pkmul2(lo2(a), lo2(b)), pkmul2(hi2(a), hi2(b)));
}

// o = tanh(a)*sigmoid(b); af, ag arrive pre-scaled by -2log2e / -log2e
__device__ __forceinline__ f32x4 gate4(f32x4 af, f32x4 ag, f32x2 one) {
    f32x4 E1, E2, rc;
    E1.x = fexp2(af.x); E1.y = fexp2(af.y); E1.z = fexp2(af.z); E1.w = fexp2(af.w);
    E2.x = fexp2(ag.x); E2.y = fexp2(ag.y); E2.z = fexp2(ag.z); E2.w = fexp2(ag.w);
    f32x4 d1  = padd_s(one, E1);
    f32x4 den = pfma_v(E2, d1, d1);
    f32x4 num = psub_s(one, E1);
    rc.x = frcp(den.x); rc.y = frcp(den.y); rc.z = frcp(den.z); rc.w = frcp(den.w);
    return pmul_v(num, rc);
}
__device__ __forceinline__ float mulaw(float v, float c1wv, float c1bv, float c2wv, float c2bv) {
    float a  = __builtin_fmaf(c1wv, fmaxf(v, 0.0f), c1bv);
    float b2 = __builtin_fmaf(c2wv, fmaxf(a, 0.0f), c2bv);
    float m  = fexp2(fabsf(b2) * 8.0f) - 1.0f;
    return copysignf(m * (1.0f / 255.0f), b2);
}

// One dilation cycle (10 layers, d=1..512). GEOMETRY: 512 threads x 6 groups
// (same CHUNK/HALO/work as the 1024x3 version) -> 256 blocks = 2 blocks/CU,
// so one block's __syncthreads() stall is filled by the other block's waves.
// Thread owns groups G = tid + 512w (w=0,1: halo; w=2..5: valid) as f16x2
// pairs; LDS holds packed words, double-buffered, ONE barrier per layer.
// Reach-based halo skip: layer k's output only needed at groups G >= 2<<k.
// Zero padding: global t<0 <=> (chunk==0 && w<2); f16 zero is exact.
// NOTE: launch_bounds (512,4) -> VGPR cap 128 (2 blocks/CU); do NOT request
// more waves (round-5 spill-storm lesson).
template <int STAGE>
__global__ __launch_bounds__(NTHREADS, 4)
void stage_kernel(const void* __restrict__ in_,
                  const float* __restrict__ cw, const float* __restrict__ cb,
                  const float* __restrict__ fw, const float* __restrict__ fb,
                  const float* __restrict__ gw, const float* __restrict__ gb,
                  const float* __restrict__ rw, const float* __restrict__ rb,
                  uint2* __restrict__ hout, uint2* __restrict__ skbuf,
                  float* __restrict__ pout,
                  const float* __restrict__ c1w, const float* __restrict__ c1b,
                  const float* __restrict__ c2w, const float* __restrict__ c2b,
                  float2* __restrict__ blockstats)
{
    __shared__ uint2 bufl[2][NGROUPS];       // 2 x 24 KB packed-f16 tap buffers
    __shared__ float red[NTHREADS / 64];

    const int tid = threadIdx.x;
    const int bid = blockIdx.x;
    const int row = bid / CHUNKS_PER_ROW;
    const int chunk = bid % CHUNKS_PER_ROW;
    const int rowbase = row * T_LEN;
    const int base_t = chunk * CHUNK;
    const bool first = (chunk == 0);
    const f16x2 HZ = hsplat(0.0f);

    // ---- load own groups + publish packed taps to buf 0 ----
    f16x2 hA[NG], hB[NG];
    if (STAGE == 0) {
        const float* inb = (const float*)in_ + rowbase + base_t - HALO;
        #pragma unroll
        for (int w = 0; w < NG; ++w) {
            int G = tid + w * NTHREADS;
            if (w < 2 && first) { hA[w] = HZ; hB[w] = HZ; }
            else {
                f32x4 v = *(const f32x4*)(inb + 4 * G);
                hA[w] = pkrtz(v.x, v.y);
                hB[w] = pkrtz(v.z, v.w);
            }
            bufl[0][G] = make_uint2(b32(hA[w]), b32(hB[w]));
        }
    } else {
        const uint2* inb = (const uint2*)in_ + ((rowbase + base_t - HALO) >> 2);
        #pragma unroll
        for (int w = 0; w < NG; ++w) {
            int G = tid + w * NTHREADS;
            uint2 u = (w < 2 && first) ? make_uint2(0u, 0u) : inb[G];
            bufl[0][G] = u;
            hA[w] = hbits(u.x); hB[w] = hbits(u.y);
        }
    }
    // skip accumulators for valid groups w=2..5, packed f16
    f16x2 sA[4], sB[4];
    const int skb = ((rowbase + base_t) >> 2) + tid;
    if (STAGE == 0) {
        #pragma unroll
        for (int j = 0; j < 4; ++j) { sA[j] = HZ; sB[j] = HZ; }
    } else {
        #pragma unroll
        for (int j = 0; j < 4; ++j) {
            uint2 u = skbuf[skb + j * NTHREADS];
            sA[j] = hbits(u.x); sB[j] = hbits(u.y);
        }
    }
    __syncthreads();

    const f32x2 ONE = pair(1.0f);

    if (STAGE == 0) {
        // causal conv (d=1); weight for tap distance m is cw[4-m]
        const f16x2 C0 = hsplat(cw[4]), C1 = hsplat(cw[3]), C2 = hsplat(cw[2]),
                    C3 = hsplat(cw[1]), C4 = hsplat(cw[0]), BB = hsplat(cb[0]);
        #pragma unroll
        for (int w = 0; w < NG; ++w) {
            int G = tid + w * NTHREADS;
            int gm = G - 1; if (w == 0) gm = gm < 0 ? 0 : gm;  // junk-in-halo OK
            uint2 P = bufl[0][gm];
            unsigned uA = b32(hA[w]), uB = b32(hB[w]);
            unsigned t1A = __builtin_amdgcn_perm(uA, P.y, 0x05040302u);
            unsigned t1B = __builtin_amdgcn_perm(uB, uA, 0x05040302u);
            unsigned t3A = __builtin_amdgcn_perm(P.y, P.x, 0x05040302u);
            f16x2 aA = hfma(C0, hA[w], BB);
            f16x2 aB = hfma(C0, hB[w], BB);
            aA = hfma(C1, hbits(t1A), aA); aB = hfma(C1, hbits(t1B), aB);
            aA = hfma(C2, hbits(P.y), aA); aB = hfma(C2, hbits(uA), aB);
            aA = hfma(C3, hbits(t3A), aA); aB = hfma(C3, hbits(t1A), aB);
            aA = hfma(C4, hbits(P.x), aA); aB = hfma(C4, hbits(P.y), aB);
            if (w < 2 && first) { aA = HZ; aB = HZ; }
            hA[w] = aA; hB[w] = aB;
            bufl[1][G] = make_uint2(b32(aA), b32(aB));
        }
        __syncthreads();
    }

    // ---- 10 dilated gated layers, one barrier each; c compile-time ----
    #pragma unroll
    for (int k = 0; k < 10; ++k) {
        const int c = (STAGE == 0) ? ((k + 1) & 1) : (k & 1);
        const int d = 1 << k;
        const int L = STAGE * 10 + k;
        const float* fwL = fw + 5 * L;
        const float* gwL = gw + 5 * L;
        const f16x2 WF0 = hsplat(fwL[4] * NEG2LOG2E), WF1 = hsplat(fwL[3] * NEG2LOG2E),
                    WF2 = hsplat(fwL[2] * NEG2LOG2E), WF3 = hsplat(fwL[1] * NEG2LOG2E),
                    WF4 = hsplat(fwL[0] * NEG2LOG2E);
        const f16x2 WG0 = hsplat(gwL[4] * NEGLOG2E), WG1 = hsplat(gwL[3] * NEGLOG2E),
                    WG2 = hsplat(gwL[2] * NEGLOG2E), WG3 = hsplat(gwL[1] * NEGLOG2E),
                    WG4 = hsplat(gwL[0] * NEGLOG2E);
        const f16x2 FB = hsplat(fb[L] * NEG2LOG2E), GB = hsplat(gb[L] * NEGLOG2E);
        const f16x2 RW = hsplat(rw[L]), RB = hsplat(rb[L]);
        const uint2* __restrict__ bufc = bufl[c];
        uint2* __restrict__ bufd = bufl[c ^ 1];

        #pragma unroll
        for (int w = 0; w < NG; ++w) {
            const int G = tid + w * NTHREADS;
            // reach skip: only halo groups (G<1024) ever satisfy G < 2<<k
            if (w < 2 && G < (2 << k)) continue;
            f16x2 cA = hA[w], cB = hB[w];
            f16x2 t1a, t1b, t2a, t2b, t3a, t3b, t4a, t4b;
            if (d >= 4) {
                const int DG = d >> 2;
                const uint2* bp = bufc + (G - 4 * DG);
                uint2 U4 = bp[0], U3 = bp[DG], U2 = bp[2 * DG], U1 = bp[3 * DG];
                t1a = hbits(U1.x); t1b = hbits(U1.y);
                t2a = hbits(U2.x); t2b = hbits(U2.y);
                t3a = hbits(U3.x); t3b = hbits(U3.y);
                t4a = hbits(U4.x); t4b = hbits(U4.y);
            } else if (d == 1) {
                uint2 P = bufc[G - 1];
                unsigned uA = b32(cA);
                unsigned w1A = __builtin_amdgcn_perm(uA, P.y, 0x05040302u);
                unsigned w1B = __builtin_amdgcn_perm(b32(cB), uA, 0x05040302u);
                unsigned w3A = __builtin_amdgcn_perm(P.y, P.x, 0x05040302u);
                t1a = hbits(w1A); t1b = hbits(w1B);
                t2a = hbits(P.y); t2b = cA;
                t3a = hbits(w3A); t3b = hbits(w1A);
                t4a = hbits(P.x); t4b = hbits(P.y);
            } else { // d == 2 — all word-aligned
                uint2 P = bufc[G - 1], Q = bufc[G - 2];
                t1a = hbits(P.y); t1b = cA;
                t2a = hbits(P.x); t2b = hbits(P.y);
                t3a = hbits(Q.y); t3b = hbits(P.x);
                t4a = hbits(Q.x); t4b = hbits(Q.y);
            }
            f16x2 afA = hfma(WF0, cA, FB), afB = hfma(WF0, cB, FB);
            afA = hfma(WF1, t1a, afA); afB = hfma(WF1, t1b, afB);
            afA = hfma(WF2, t2a, afA); afB = hfma(WF2, t2b, afB);
            afA = hfma(WF3, t3a, afA); afB = hfma(WF3, t3b, afB);
            afA = hfma(WF4, t4a, afA); afB = hfma(WF4, t4b, afB);
            f16x2 agA = hfma(WG0, cA, GB), agB = hfma(WG0, cB, GB);
            agA = hfma(WG1, t1a, agA); agB = hfma(WG1, t1b, agB);
            agA = hfma(WG2, t2a, agA); agB = hfma(WG2, t2b, agB);
            agA = hfma(WG3, t3a, agA); agB = hfma(WG3, t3b, agB);
            agA = hfma(WG4, t4a, agA); agB = hfma(WG4, t4b, agB);
            f32x4 o = gate4(h2f4(afA, afB), h2f4(agA, agB), ONE);
            f16x2 oA = pkrtz(o.x, o.y), oB = pkrtz(o.z, o.w);
            f16x2 nA = hfma(RW, oA, cA + RB);
            f16x2 nB = hfma(RW, oB, cB + RB);
            if (w < 2 && first) { nA = HZ; nB = HZ; }    // t<0 padding exact 0
            hA[w] = nA; hB[w] = nB;
            if (k < 9) bufd[G] = make_uint2(b32(nA), b32(nB));
            if (w >= 2) { sA[w - 2] = sA[w - 2] + oA; sB[w - 2] = sB[w - 2] + oB; }
        }
        if (k < 9) __syncthreads();
    }

    if (STAGE < 2) {
        uint2* hp = hout + ((rowbase + base_t) >> 2);
        #pragma unroll
        for (int j = 0; j < 4; ++j) {
            hp[tid + j * NTHREADS] = make_uint2(b32(hA[j + 2]), b32(hB[j + 2]));
            skbuf[skb + j * NTHREADS] = make_uint2(b32(sA[j]), b32(sB[j]));
        }
    } else {
        // fused epilogue + per-block (max, sum-exp) stats
        const float c1wv = c1w[0], c1bv = c1b[0], c2wv = c2w[0], c2bv = c2b[0];
        f32x4 p[4];
        float pmax = -3.0e38f;
        #pragma unroll
        for (int j = 0; j < 4; ++j) {
            f32x4 skv = h2f4(sA[j], sB[j]);
            p[j].x = mulaw(skv.x, c1wv, c1bv, c2wv, c2bv);
            p[j].y = mulaw(skv.y, c1wv, c1bv, c2wv, c2bv);
            p[j].z = mulaw(skv.z, c1wv, c1bv, c2wv, c2bv);
            p[j].w = mulaw(skv.w, c1wv, c1bv, c2wv, c2bv);
            *(f32x4*)(pout + rowbase + base_t + j * (4 * NTHREADS) + 4 * tid) = p[j];
            pmax = fmaxf(pmax, fmaxf(fmaxf(p[j].x, p[j].y), fmaxf(p[j].z, p[j].w)));
        }
        #pragma unroll
        for (int off = 32; off; off >>= 1) pmax = fmaxf(pmax, __shfl_xor(pmax, off, 64));
        if ((tid & 63) == 0) red[tid >> 6] = pmax;
        __syncthreads();
        float bmax = red[0];
        #pragma unroll
        for (int i = 1; i < NTHREADS / 64; ++i) bmax = fmaxf(bmax, red[i]);
        __syncthreads();   // red reused below

        float ps = 0.0f;
        #pragma unroll
        for (int j = 0; j < 4; ++j) {
            ps += fexp2((p[j].x - bmax) * LOG2E) + fexp2((p[j].y - bmax) * LOG2E)
                + fexp2((p[j].z - bmax) * LOG2E) + fexp2((p[j].w - bmax) * LOG2E);
        }
        #pragma unroll
        for (int off = 32; off; off >>= 1) ps += __shfl_xor(ps, off, 64);
        if ((tid & 63) == 0) red[tid >> 6] = ps;
        __syncthreads();
        if (tid == 0) {
            float s = 0.0f;
            #pragma unroll
            for (int i = 0; i < NTHREADS / 64; ++i) s += red[i];
            blockstats[bid] = make_float2(bmax, s);
        }
    }
}

// 8 blocks (one per row) x 64 threads: reduce 32 block-stats -> (rowmax, 1/rowsum)
__global__ __launch_bounds__(64)
void combine_kernel(const float2* __restrict__ bs, float2* __restrict__ rs)
{
    const int row = blockIdx.x;
    const int lane = threadIdx.x;
    float bm = -3.0e38f, s = 0.0f;
    if (lane < CHUNKS_PER_ROW) {
        float2 v = bs[row * CHUNKS_PER_ROW + lane];
        bm = v.x; s = v.y;
    }
    float m = bm;
    #pragma unroll
    for (int off = 32; off; off >>= 1) m = fmaxf(m, __shfl_xor(m, off, 64));
    float cc = s * fexp2((bm - m) * LOG2E);
    #pragma unroll
    for (int off = 32; off; off >>= 1) cc += __shfl_xor(cc, off, 64);
    if (lane == 0) rs[row] = make_float2(m, 1.0f / cc);
}

__global__ __launch_bounds__(1024)
void norm_kernel(float* __restrict__ p, const float2* __restrict__ rs)
{
    const int tid = threadIdx.x, bid = blockIdx.x;
    const int row = bid / CHUNKS_PER_ROW;
    const float2 st = rs[row];
    const int base = row * T_LEN + (bid % CHUNKS_PER_ROW) * CHUNK + 4 * tid;
    #pragma unroll
    for (int part = 0; part < 2; ++part) {
        float* q = p + base + part * 4096;
        f32x4 v = *(const f32x4*)q;
        v.x = fexp2((v.x - st.x) * LOG2E) * st.y;
        v.y = fexp2((v.y - st.x) * LOG2E) * st.y;
        v.z = fexp2((v.z - st.x) * LOG2E) * st.y;
        v.w = fexp2((v.w - st.x) * LOG2E) * st.y;
        *(f32x4*)q = v;
    }
}

extern "C" void kernel_launch(void* const* d_in, const int* in_sizes, int n_in,
                              void* d_out, int out_size, void* d_ws, size_t ws_size,
                              hipStream_t stream)
{
    (void)in_sizes; (void)n_in; (void)out_size; (void)ws_size;
    const float* x   = (const float*)d_in[0];
    const float* cw  = (const float*)d_in[1];
    const float* cb  = (const float*)d_in[2];
    const float* fw  = (const float*)d_in[3];
    const float* fb  = (const float*)d_in[4];
    const float* gw  = (const float*)d_in[5];
    const float* gb  = (const float*)d_in[6];
    const float* rw  = (const float*)d_in[7];
    const float* rb  = (const float*)d_in[8];
    const float* c1w = (const float*)d_in[9];
    const float* c1b = (const float*)d_in[10];
    const float* c2w = (const float*)d_in[11];
    const float* c2b = (const float*)d_in[12];
    float* out = (float*)d_out;

    const size_t NTOT = (size_t)B_SZ * T_LEN;
    uint2*  hA = (uint2*)d_ws;                                  // 4.2 MB packed f16
    uint2*  hB = (uint2*)((char*)d_ws + 2 * NTOT);              // 4.2 MB
    uint2*  sk = (uint2*)((char*)d_ws + 4 * NTOT);              // 4.2 MB packed f16
    float2* bs = (float2*)((char*)d_ws + 6 * NTOT);             // 2 KB
    float2* rs = (float2*)((char*)d_ws + 6 * NTOT + 8192);      // 64 B

    stage_kernel<0><<<NBLOCKS, NTHREADS, 0, stream>>>(x,  cw, cb, fw, fb, gw, gb, rw, rb,
                                                      hA, sk, out, c1w, c1b, c2w, c2b, bs);
    stage_kernel<1><<<NBLOCKS, NTHREADS, 0, stream>>>(hA, cw, cb, fw, fb, gw, gb, rw, rb,
                                                      hB, sk, out, c1w, c1b, c2w, c2b, bs);
    stage_kernel<2><<<NBLOCKS, NTHREADS, 0, stream>>>(hB, cw, cb, fw, fb, gw, gb, rw, rb,
                                                      nullptr, sk, out, c1w, c1b, c2w, c2b, bs);
    combine_kernel<<<B_SZ, 64, 0, stream>>>(bs, rs);
    norm_kernel<<<NBLOCKS, 1024, 0, stream>>>(out, rs);
}

// Round 14
// 74.331 us; speedup vs baseline: 3.4374x; 1.0830x over previous
//
#include <hip/hip_runtime.h>

#define T_LEN 262144
#define B_SZ 8
#define CHUNK 8192
#define HALO 4096
#define NTHREADS 1024
#define NGROUPS ((CHUNK + HALO) / 4)    // 3072 4-element groups per frame
#define CHUNKS_PER_ROW (T_LEN / CHUNK)  // 32
#define NBLOCKS (B_SZ * CHUNKS_PER_ROW) // 256
#define LOG2E 1.4426950408889634f
#define NEG2LOG2E (-2.8853900817779268f)
#define NEGLOG2E  (-1.4426950408889634f)

typedef float f32x2 __attribute__((ext_vector_type(2)));
typedef float f32x4 __attribute__((ext_vector_type(4)));
typedef _Float16 f16x2 __attribute__((ext_vector_type(2)));
typedef __fp16 fp16x2 __attribute__((ext_vector_type(2)));

__device__ __forceinline__ float frcp(float x)  { return __builtin_amdgcn_rcpf(x); }
__device__ __forceinline__ float fexp2(float x) { return __builtin_amdgcn_exp2f(x); }
__device__ __forceinline__ f32x2 pair(float s)  { f32x2 r = {s, s}; return r; }
__device__ __forceinline__ f32x2 lo2(f32x4 v)   { return __builtin_shufflevector(v, v, 0, 1); }
__device__ __forceinline__ f32x2 hi2(f32x4 v)   { return __builtin_shufflevector(v, v, 2, 3); }
__device__ __forceinline__ f32x4 cat4(f32x2 a, f32x2 b) {
    f32x4 r; r.x = a.x; r.y = a.y; r.z = b.x; r.w = b.y; return r;
}
__device__ __forceinline__ unsigned b32(f16x2 v) { return __builtin_bit_cast(unsigned, v); }
__device__ __forceinline__ f16x2 hbits(unsigned u) { return __builtin_bit_cast(f16x2, u); }
__device__ __forceinline__ f16x2 hsplat(float s) { _Float16 h = (_Float16)s; f16x2 r = {h, h}; return r; }
__device__ __forceinline__ f16x2 hfma(f16x2 a, f16x2 b, f16x2 c) { return __builtin_elementwise_fma(a, b, c); }
__device__ __forceinline__ f16x2 pkrtz(float x, float y) {
    fp16x2 t = __builtin_amdgcn_cvt_pkrtz(x, y);
    return __builtin_bit_cast(f16x2, t);
}
__device__ __forceinline__ f32x4 h2f4(f16x2 a, f16x2 b) {
    f32x2 lo = __builtin_convertvector(a, f32x2);
    f32x2 hi = __builtin_convertvector(b, f32x2);
    return cat4(lo, hi);
}

// packed-FP32 VOP3P asm (round-8 lesson: sources must be VGPRs, never SGPRs)
__device__ __forceinline__ f32x2 pkfma2(f32x2 a, f32x2 b, f32x2 c) {
    f32x2 d;
    asm("v_pk_fma_f32 %0, %1, %2, %3" : "=v"(d) : "v"(a), "v"(b), "v"(c));
    return d;
}
__device__ __forceinline__ f32x2 pkadd2(f32x2 a, f32x2 b) {
    f32x2 d;
    asm("v_pk_add_f32 %0, %1, %2" : "=v"(d) : "v"(a), "v"(b));
    return d;
}
__device__ __forceinline__ f32x2 pksub2(f32x2 a, f32x2 b) {  // a - b
    f32x2 d;
    asm("v_pk_add_f32 %0, %1, %2 neg_lo:[0,1] neg_hi:[0,1]" : "=v"(d) : "v"(a), "v"(b));
    return d;
}
__device__ __forceinline__ f32x2 pkmul2(f32x2 a, f32x2 b) {
    f32x2 d;
    asm("v_pk_mul_f32 %0, %1, %2" : "=v"(d) : "v"(a), "v"(b));
    return d;
}
__device__ __forceinline__ f32x4 pfma_v(f32x4 a, f32x4 b, f32x4 c) {
    return cat4(pkfma2(lo2(a), lo2(b), lo2(c)), pkfma2(hi2(a), hi2(b), hi2(c)));
}
__device__ __forceinline__ f32x4 padd_s(f32x2 s, f32x4 b) {
    return cat4(pkadd2(s, lo2(b)), pkadd2(s, hi2(b)));
}
__device__ __forceinline__ f32x4 psub_s(f32x2 s, f32x4 b) {  // s - b
    return cat4(pksub2(s, lo2(b)), pksub2(s, hi2(b)));
}
__device__ __forceinline__ f32x4 pmul_v(f32x4 a, f32x4 b) {
    return cat4(pkmul2(lo2(a), lo2(b)), pkmul2(hi2(a), hi2(b)));
}

// o = tanh(a)*sigmoid(b); af, ag arrive pre-scaled by -2log2e / -log2e
__device__ __forceinline__ f32x4 gate4(f32x4 af, f32x4 ag, f32x2 one) {
    f32x4 E1, E2, rc;
    E1.x = fexp2(af.x); E1.y = fexp2(af.y); E1.z = fexp2(af.z); E1.w = fexp2(af.w);
    E2.x = fexp2(ag.x); E2.y = fexp2(ag.y); E2.z = fexp2(ag.z); E2.w = fexp2(ag.w);
    f32x4 d1  = padd_s(one, E1);
    f32x4 den = pfma_v(E2, d1, d1);
    f32x4 num = psub_s(one, E1);
    rc.x = frcp(den.x); rc.y = frcp(den.y); rc.z = frcp(den.z); rc.w = frcp(den.w);
    return pmul_v(num, rc);
}
__device__ __forceinline__ float mulaw(float v, float c1wv, float c1bv, float c2wv, float c2bv) {
    float a  = __builtin_fmaf(c1wv, fmaxf(v, 0.0f), c1bv);
    float b2 = __builtin_fmaf(c2wv, fmaxf(a, 0.0f), c2bv);
    float m  = fexp2(fabsf(b2) * 8.0f) - 1.0f;
    return copysignf(m * (1.0f / 255.0f), b2);
}

// One dilation cycle (10 layers, d=1..512) — round-11 structure (best: 77.4us).
// Thread owns 3 groups (4 elems each) as f16x2 pairs; LDS double-buffered
// packed words, ONE barrier per layer; reach-based halo skip; packed-f16
// inter-stage handoff. STAGE 2 now also STORES pre-softmax p as packed f16
// (into the free hA buffer) and computes block stats from the ROUNDED values.
// NOTE: launch_bounds min-waves stays 4 — 8 clamps VGPR to 32 -> spill storm.
template <int STAGE>
__global__ __launch_bounds__(NTHREADS, 4)
void stage_kernel(const void* __restrict__ in_,
                  const float* __restrict__ cw, const float* __restrict__ cb,
                  const float* __restrict__ fw, const float* __restrict__ fb,
                  const float* __restrict__ gw, const float* __restrict__ gb,
                  const float* __restrict__ rw, const float* __restrict__ rb,
                  uint2* __restrict__ hout, uint2* __restrict__ skbuf,
                  uint2* __restrict__ pout,
                  const float* __restrict__ c1w, const float* __restrict__ c1b,
                  const float* __restrict__ c2w, const float* __restrict__ c2b,
                  float2* __restrict__ blockstats)
{
    __shared__ uint2 bufl[2][NGROUPS];       // 2 x 24 KB packed-f16 tap buffers
    __shared__ float red[NTHREADS / 64];

    const int tid = threadIdx.x;
    const int bid = blockIdx.x;
    const int row = bid / CHUNKS_PER_ROW;
    const int chunk = bid % CHUNKS_PER_ROW;
    const int rowbase = row * T_LEN;
    const int base_t = chunk * CHUNK;
    const bool first = (chunk == 0);
    const f16x2 HZ = hsplat(0.0f);

    // ---- load own groups + publish packed taps to buf 0 ----
    f16x2 hA[3], hB[3];
    if (STAGE == 0) {
        const float* inb = (const float*)in_ + rowbase + base_t - HALO;
        #pragma unroll
        for (int w = 0; w < 3; ++w) {
            int G = tid + w * NTHREADS;
            if (w == 0 && first) { hA[w] = HZ; hB[w] = HZ; }
            else {
                f32x4 v = *(const f32x4*)(inb + 4 * G);
                hA[w] = pkrtz(v.x, v.y);
                hB[w] = pkrtz(v.z, v.w);
            }
            bufl[0][G] = make_uint2(b32(hA[w]), b32(hB[w]));
        }
    } else {
        const uint2* inb = (const uint2*)in_ + ((rowbase + base_t - HALO) >> 2);
        #pragma unroll
        for (int w = 0; w < 3; ++w) {
            int G = tid + w * NTHREADS;
            uint2 u = (w == 0 && first) ? make_uint2(0u, 0u) : inb[G];
            bufl[0][G] = u;
            hA[w] = hbits(u.x); hB[w] = hbits(u.y);
        }
    }
    // skip accumulators for w=1,2 (valid region), packed f16
    f16x2 s1A, s1B, s2A, s2B;
    const int skb = ((rowbase + base_t) >> 2) + tid;
    if (STAGE == 0) { s1A = HZ; s1B = HZ; s2A = HZ; s2B = HZ; }
    else {
        uint2 u1 = skbuf[skb], u2 = skbuf[skb + 1024];
        s1A = hbits(u1.x); s1B = hbits(u1.y);
        s2A = hbits(u2.x); s2B = hbits(u2.y);
    }
    __syncthreads();

    const f32x2 ONE = pair(1.0f);

    if (STAGE == 0) {
        // causal conv (d=1); weight for tap distance m is cw[4-m]
        const f16x2 C0 = hsplat(cw[4]), C1 = hsplat(cw[3]), C2 = hsplat(cw[2]),
                    C3 = hsplat(cw[1]), C4 = hsplat(cw[0]), BB = hsplat(cb[0]);
        #pragma unroll
        for (int w = 0; w < 3; ++w) {
            int G = tid + w * NTHREADS;
            int gm = G - 1; if (w == 0) gm = gm < 0 ? 0 : gm;  // junk-in-halo OK
            uint2 P = bufl[0][gm];
            unsigned uA = b32(hA[w]), uB = b32(hB[w]);
            unsigned t1A = __builtin_amdgcn_perm(uA, P.y, 0x05040302u);
            unsigned t1B = __builtin_amdgcn_perm(uB, uA, 0x05040302u);
            unsigned t3A = __builtin_amdgcn_perm(P.y, P.x, 0x05040302u);
            f16x2 aA = hfma(C0, hA[w], BB);
            f16x2 aB = hfma(C0, hB[w], BB);
            aA = hfma(C1, hbits(t1A), aA); aB = hfma(C1, hbits(t1B), aB);
            aA = hfma(C2, hbits(P.y), aA); aB = hfma(C2, hbits(uA), aB);
            aA = hfma(C3, hbits(t3A), aA); aB = hfma(C3, hbits(t1A), aB);
            aA = hfma(C4, hbits(P.x), aA); aB = hfma(C4, hbits(P.y), aB);
            if (w == 0 && first) { aA = HZ; aB = HZ; }
            hA[w] = aA; hB[w] = aB;
            bufl[1][G] = make_uint2(b32(aA), b32(aB));
        }
        __syncthreads();
    }

    // ---- 10 dilated gated layers, one barrier each; c compile-time ----
    #pragma unroll
    for (int k = 0; k < 10; ++k) {
        const int c = (STAGE == 0) ? ((k + 1) & 1) : (k & 1);
        const int d = 1 << k;
        const int L = STAGE * 10 + k;
        const float* fwL = fw + 5 * L;
        const float* gwL = gw + 5 * L;
        const f16x2 WF0 = hsplat(fwL[4] * NEG2LOG2E), WF1 = hsplat(fwL[3] * NEG2LOG2E),
                    WF2 = hsplat(fwL[2] * NEG2LOG2E), WF3 = hsplat(fwL[1] * NEG2LOG2E),
                    WF4 = hsplat(fwL[0] * NEG2LOG2E);
        const f16x2 WG0 = hsplat(gwL[4] * NEGLOG2E), WG1 = hsplat(gwL[3] * NEGLOG2E),
                    WG2 = hsplat(gwL[2] * NEGLOG2E), WG3 = hsplat(gwL[1] * NEGLOG2E),
                    WG4 = hsplat(gwL[0] * NEGLOG2E);
        const f16x2 FB = hsplat(fb[L] * NEG2LOG2E), GB = hsplat(gb[L] * NEGLOG2E);
        const f16x2 RW = hsplat(rw[L]), RB = hsplat(rb[L]);
        const uint2* __restrict__ bufc = bufl[c];
        uint2* __restrict__ bufd = bufl[c ^ 1];

        #pragma unroll
        for (int w = 0; w < 3; ++w) {
            const int G = tid + w * NTHREADS;
            if (w == 0 && tid < (2 << k)) continue;  // reach expired (k=9: all of w=0)
            f16x2 cA = hA[w], cB = hB[w];
            f16x2 t1a, t1b, t2a, t2b, t3a, t3b, t4a, t4b;
            if (d >= 4) {
                const int DG = d >> 2;
                const uint2* bp = bufc + (G - 4 * DG);
                uint2 U4 = bp[0], U3 = bp[DG], U2 = bp[2 * DG], U1 = bp[3 * DG];
                t1a = hbits(U1.x); t1b = hbits(U1.y);
                t2a = hbits(U2.x); t2b = hbits(U2.y);
                t3a = hbits(U3.x); t3b = hbits(U3.y);
                t4a = hbits(U4.x); t4b = hbits(U4.y);
            } else if (d == 1) {
                uint2 P = bufc[G - 1];
                unsigned uA = b32(cA);
                unsigned w1A = __builtin_amdgcn_perm(uA, P.y, 0x05040302u);
                unsigned w1B = __builtin_amdgcn_perm(b32(cB), uA, 0x05040302u);
                unsigned w3A = __builtin_amdgcn_perm(P.y, P.x, 0x05040302u);
                t1a = hbits(w1A); t1b = hbits(w1B);
                t2a = hbits(P.y); t2b = cA;
                t3a = hbits(w3A); t3b = hbits(w1A);
                t4a = hbits(P.x); t4b = hbits(P.y);
            } else { // d == 2 — all word-aligned
                uint2 P = bufc[G - 1], Q = bufc[G - 2];
                t1a = hbits(P.y); t1b = cA;
                t2a = hbits(P.x); t2b = hbits(P.y);
                t3a = hbits(Q.y); t3b = hbits(P.x);
                t4a = hbits(Q.x); t4b = hbits(Q.y);
            }
            f16x2 afA = hfma(WF0, cA, FB), afB = hfma(WF0, cB, FB);
            afA = hfma(WF1, t1a, afA); afB = hfma(WF1, t1b, afB);
            afA = hfma(WF2, t2a, afA); afB = hfma(WF2, t2b, afB);
            afA = hfma(WF3, t3a, afA); afB = hfma(WF3, t3b, afB);
            afA = hfma(WF4, t4a, afA); afB = hfma(WF4, t4b, afB);
            f16x2 agA = hfma(WG0, cA, GB), agB = hfma(WG0, cB, GB);
            agA = hfma(WG1, t1a, agA); agB = hfma(WG1, t1b, agB);
            agA = hfma(WG2, t2a, agA); agB = hfma(WG2, t2b, agB);
            agA = hfma(WG3, t3a, agA); agB = hfma(WG3, t3b, agB);
            agA = hfma(WG4, t4a, agA); agB = hfma(WG4, t4b, agB);
            f32x4 o = gate4(h2f4(afA, afB), h2f4(agA, agB), ONE);
            f16x2 oA = pkrtz(o.x, o.y), oB = pkrtz(o.z, o.w);
            f16x2 nA = hfma(RW, oA, cA + RB);
            f16x2 nB = hfma(RW, oB, cB + RB);
            if (w == 0 && first) { nA = HZ; nB = HZ; }   // t<0 pad exact 0
            hA[w] = nA; hB[w] = nB;
            if (k < 9) bufd[G] = make_uint2(b32(nA), b32(nB));
            if (w == 1) { s1A = s1A + oA; s1B = s1B + oB; }
            if (w == 2) { s2A = s2A + oA; s2B = s2B + oB; }
        }
        if (k < 9) __syncthreads();
    }

    if (STAGE < 2) {
        uint2* hp = hout + ((rowbase + base_t) >> 2);
        hp[tid]        = make_uint2(b32(hA[1]), b32(hB[1]));   // packed f16 handoff
        hp[tid + 1024] = make_uint2(b32(hA[2]), b32(hB[2]));
        skbuf[skb]        = make_uint2(b32(s1A), b32(s1B));
        skbuf[skb + 1024] = make_uint2(b32(s2A), b32(s2B));
    } else {
        // fused epilogue: mu-law -> packed-f16 store + per-block stats
        // (stats computed from the ROUNDED values for self-consistency)
        const float c1wv = c1w[0], c1bv = c1b[0], c2wv = c2w[0], c2bv = c2b[0];
        f32x4 sk1 = h2f4(s1A, s1B), sk2 = h2f4(s2A, s2B);
        f32x4 p1, p2;
        p1.x = mulaw(sk1.x, c1wv, c1bv, c2wv, c2bv);
        p1.y = mulaw(sk1.y, c1wv, c1bv, c2wv, c2bv);
        p1.z = mulaw(sk1.z, c1wv, c1bv, c2wv, c2bv);
        p1.w = mulaw(sk1.w, c1wv, c1bv, c2wv, c2bv);
        p2.x = mulaw(sk2.x, c1wv, c1bv, c2wv, c2bv);
        p2.y = mulaw(sk2.y, c1wv, c1bv, c2wv, c2bv);
        p2.z = mulaw(sk2.z, c1wv, c1bv, c2wv, c2bv);
        p2.w = mulaw(sk2.w, c1wv, c1bv, c2wv, c2bv);
        f16x2 q1A = pkrtz(p1.x, p1.y), q1B = pkrtz(p1.z, p1.w);
        f16x2 q2A = pkrtz(p2.x, p2.y), q2B = pkrtz(p2.z, p2.w);
        pout[skb]        = make_uint2(b32(q1A), b32(q1B));
        pout[skb + 1024] = make_uint2(b32(q2A), b32(q2B));
        p1 = h2f4(q1A, q1B);
        p2 = h2f4(q2A, q2B);

        float pmax = fmaxf(fmaxf(fmaxf(p1.x, p1.y), fmaxf(p1.z, p1.w)),
                           fmaxf(fmaxf(p2.x, p2.y), fmaxf(p2.z, p2.w)));
        #pragma unroll
        for (int off = 32; off; off >>= 1) pmax = fmaxf(pmax, __shfl_xor(pmax, off, 64));
        if ((tid & 63) == 0) red[tid >> 6] = pmax;
        __syncthreads();
        float bmax = red[0];
        #pragma unroll
        for (int i = 1; i < NTHREADS / 64; ++i) bmax = fmaxf(bmax, red[i]);
        __syncthreads();   // red reused below

        float ps = fexp2((p1.x - bmax) * LOG2E) + fexp2((p1.y - bmax) * LOG2E)
                 + fexp2((p1.z - bmax) * LOG2E) + fexp2((p1.w - bmax) * LOG2E)
                 + fexp2((p2.x - bmax) * LOG2E) + fexp2((p2.y - bmax) * LOG2E)
                 + fexp2((p2.z - bmax) * LOG2E) + fexp2((p2.w - bmax) * LOG2E);
        #pragma unroll
        for (int off = 32; off; off >>= 1) ps += __shfl_xor(ps, off, 64);
        if ((tid & 63) == 0) red[tid >> 6] = ps;
        __syncthreads();
        if (tid == 0) {
            float s = 0.0f;
            #pragma unroll
            for (int i = 0; i < NTHREADS / 64; ++i) s += red[i];
            blockstats[bid] = make_float2(bmax, s);
        }
    }
}

// Fused combine+norm: each block redundantly reduces its row's 32 stats
// (64 B, L2-hot) then normalizes its own 8192 elements from f16 p.
__global__ __launch_bounds__(NTHREADS)
void norm_kernel(const uint2* __restrict__ p16, const float2* __restrict__ bs,
                 float* __restrict__ out)
{
    const int tid = threadIdx.x, bid = blockIdx.x;
    const int row = bid / CHUNKS_PER_ROW;
    float m = -3.0e38f;
    #pragma unroll
    for (int j = 0; j < CHUNKS_PER_ROW; ++j)
        m = fmaxf(m, bs[row * CHUNKS_PER_ROW + j].x);
    float cc = 0.0f;
    #pragma unroll
    for (int j = 0; j < CHUNKS_PER_ROW; ++j) {
        float2 v = bs[row * CHUNKS_PER_ROW + j];
        cc += v.y * fexp2((v.x - m) * LOG2E);
    }
    const float inv = 1.0f / cc;
    const int base4 = ((row * T_LEN + (bid % CHUNKS_PER_ROW) * CHUNK) >> 2) + tid;
    #pragma unroll
    for (int part = 0; part < 2; ++part) {
        uint2 u = p16[base4 + part * NTHREADS];
        f32x4 v = h2f4(hbits(u.x), hbits(u.y));
        f32x4 q;
        q.x = fexp2((v.x - m) * LOG2E) * inv;
        q.y = fexp2((v.y - m) * LOG2E) * inv;
        q.z = fexp2((v.z - m) * LOG2E) * inv;
        q.w = fexp2((v.w - m) * LOG2E) * inv;
        *(f32x4*)(out + 4 * (base4 + part * NTHREADS)) = q;
    }
}

extern "C" void kernel_launch(void* const* d_in, const int* in_sizes, int n_in,
                              void* d_out, int out_size, void* d_ws, size_t ws_size,
                              hipStream_t stream)
{
    (void)in_sizes; (void)n_in; (void)out_size; (void)ws_size;
    const float* x   = (const float*)d_in[0];
    const float* cw  = (const float*)d_in[1];
    const float* cb  = (const float*)d_in[2];
    const float* fw  = (const float*)d_in[3];
    const float* fb  = (const float*)d_in[4];
    const float* gw  = (const float*)d_in[5];
    const float* gb  = (const float*)d_in[6];
    const float* rw  = (const float*)d_in[7];
    const float* rb  = (const float*)d_in[8];
    const float* c1w = (const float*)d_in[9];
    const float* c1b = (const float*)d_in[10];
    const float* c2w = (const float*)d_in[11];
    const float* c2b = (const float*)d_in[12];
    float* out = (float*)d_out;

    const size_t NTOT = (size_t)B_SZ * T_LEN;
    uint2*  hA = (uint2*)d_ws;                                  // 4.2 MB packed f16
    uint2*  hB = (uint2*)((char*)d_ws + 2 * NTOT);              // 4.2 MB
    uint2*  sk = (uint2*)((char*)d_ws + 4 * NTOT);              // 4.2 MB packed f16
    float2* bs = (float2*)((char*)d_ws + 6 * NTOT);             // 2 KB

    // stage2 reuses hA (free after stage1 consumed it) for packed-f16 p.
    stage_kernel<0><<<NBLOCKS, NTHREADS, 0, stream>>>(x,  cw, cb, fw, fb, gw, gb, rw, rb,
                                                      hA, sk, nullptr, c1w, c1b, c2w, c2b, bs);
    stage_kernel<1><<<NBLOCKS, NTHREADS, 0, stream>>>(hA, cw, cb, fw, fb, gw, gb, rw, rb,
                                                      hB, sk, nullptr, c1w, c1b, c2w, c2b, bs);
    stage_kernel<2><<<NBLOCKS, NTHREADS, 0, stream>>>(hB, cw, cb, fw, fb, gw, gb, rw, rb,
                                                      nullptr, sk, hA, c1w, c1b, c2w, c2b, bs);
    norm_kernel<<<NBLOCKS, NTHREADS, 0, stream>>>(hA, bs, out);
}